// Round 1
// baseline (396.792 us; speedup 1.0000x reference)
//
#include <hip/hip_runtime.h>
#include <math.h>

#define NFIELDS 10
#define VOCAB   100000
#define EDIM    8
#define BATCH   16384
#define NPAIR   45   // 10*9/2

// Round 2 experiment: pair-major restructure.
//
// Hypothesis under test: the 390 µs item-major kernel was NOT at a true HBM
// roofline (138 MB unique lines / 390 µs = ~450 GB/s = 5.6% of peak; random
// 128B fetches over ~8k banks should sustain >1.5 TB/s). Suspects in the old
// structure: per-lane divergent pair decode, dependent strided x-gathers on
// the V-address critical path, 9 idle lanes/wave, per-item shuffle tail.
//
// This version eliminates all of them:
//  K1 ffm_first : out[b] = bias + sum_i L[i, x[b,i]]        (thread/item)
//  K2 ffm_pairs : thread = (pair, item); block-uniform pair decode (scalar),
//                 dense x reads (L2-hot, 640 KB), 2x32B V gathers/lane,
//                 all 64 lanes active, atomicAdd into out[b].
//                 Pair index is the SLOW grid index -> blocks touching the
//                 same 6.4 MB slice-pair are temporally adjacent (L2/L3
//                 captures the 1.36x intra-slice line reuse).
//  K3 ffm_sigmoid: in-place epilogue.
//
// Same-stream launches serialize K1 -> K2 -> K3; no workspace, no coop launch,
// graph-capture safe. atomicAdd(float*) is a HW f32 atomic at L2 on gfx950;
// 45 adds per address over the whole kernel -> negligible contention, and
// reorder error ~1e-7 on values of magnitude ~0.01 (well under absmax tol).

__global__ __launch_bounds__(256) void ffm_first(
    const int*   __restrict__ x,     // (BATCH, NFIELDS)
    const float* __restrict__ bias,  // scalar
    const float* __restrict__ L,     // (NFIELDS, VOCAB)
    float*       __restrict__ out)   // (BATCH, 1) -- holds logits until K3
{
    const int b = blockIdx.x * 256 + threadIdx.x;
    float acc = bias[0];
    #pragma unroll
    for (int i = 0; i < NFIELDS; ++i) {
        const int xi = x[b * NFIELDS + i];
        acc += L[(size_t)i * VOCAB + (size_t)xi];
    }
    out[b] = acc;
}

__global__ __launch_bounds__(256) void ffm_pairs(
    const int*   __restrict__ x,     // (BATCH, NFIELDS)
    const float* __restrict__ V,     // (NFIELDS, NFIELDS, VOCAB, EDIM)
    float*       __restrict__ out)   // logits accumulator
{
    // grid = NPAIR * 64 blocks; pair is the slow index.
    const int pb = blockIdx.x;
    const int p  = pb >> 6;                      // pair id 0..44
    const int b  = ((pb & 63) << 8) + threadIdx.x;  // item id 0..16383

    // decode p -> (i,j), i<j. p is block-uniform -> pure scalar control flow.
    int i = 0, q = p, cnt = NFIELDS - 1;
    while (q >= cnt) { q -= cnt; ++i; --cnt; }
    const int j = i + 1 + q;

    // x reads: stride-40B dense pattern, entire x table = 640 KB (L2/L3 hot).
    const int xi = x[b * NFIELDS + i];
    const int xj = x[b * NFIELDS + j];

    const float* va = V + (((size_t)i * NFIELDS + j) * VOCAB + (size_t)xi) * EDIM;
    const float* vb = V + (((size_t)j * NFIELDS + i) * VOCAB + (size_t)xj) * EDIM;

    // rows are 32B-aligned; 4 independent 16B loads in flight per lane,
    // 128 independent lines per wave.
    const float4 a0 = ((const float4*)va)[0];
    const float4 a1 = ((const float4*)va)[1];
    const float4 b0 = ((const float4*)vb)[0];
    const float4 b1 = ((const float4*)vb)[1];

    const float dot = a0.x * b0.x + a0.y * b0.y + a0.z * b0.z + a0.w * b0.w
                    + a1.x * b1.x + a1.y * b1.y + a1.z * b1.z + a1.w * b1.w;

    atomicAdd(&out[b], dot);
}

__global__ __launch_bounds__(256) void ffm_sigmoid(
    float* __restrict__ out)
{
    const int b = blockIdx.x * 256 + threadIdx.x;
    const float logit = out[b];
    out[b] = 1.0f / (1.0f + expf(-logit));
}

extern "C" void kernel_launch(void* const* d_in, const int* in_sizes, int n_in,
                              void* d_out, int out_size, void* d_ws, size_t ws_size,
                              hipStream_t stream) {
    const int*   x    = (const int*)  d_in[0];
    const float* bias = (const float*)d_in[1];
    const float* L    = (const float*)d_in[2];
    const float* V    = (const float*)d_in[3];
    float*       out  = (float*)d_out;

    // K1: init logits with bias + first-order terms.
    ffm_first<<<BATCH / 256, 256, 0, stream>>>(x, bias, L, out);

    // K2: 45 pairs x 64 item-chunks of 256.
    ffm_pairs<<<NPAIR * 64, 256, 0, stream>>>(x, V, out);

    // K3: sigmoid epilogue in place.
    ffm_sigmoid<<<BATCH / 256, 256, 0, stream>>>(out);
}

// Round 2
// 390.819 us; speedup vs baseline: 1.0153x; 1.0153x over previous
//
#include <hip/hip_runtime.h>
#include <math.h>

#define NFIELDS 10
#define VOCAB   100000
#define EDIM    8
#define BATCH   16384
#define NPAIR   45   // 10*9/2

// Round 3: revert to the measured-best single-kernel item-major structure
// (round-1, 390.3 us) with address-math polish.
//
// Evidence from round-2 rocprof: the timed window is floored by harness
// poison-fills (fillBufferAligned, 1.28 GB @ 6.6 TB/s, ~193 us each; our
// kernels never appear in top-5 => each < 192.7 us, while the graph measures
// ~397 us). Two radically different kernel structures measured within 1.7%.
// Conclusion: our kernels contribute only single-digit us; minimize additive
// cost => ONE launch, no atomics, no extra out-buffer passes.
//
// Structure: one 64-lane wave per batch item.
//   lanes [0,45): pair (i,j) -> dot(V[i,j,x_i,:], V[j,i,x_j,:]) via 4x16B loads
//   lanes [45,55): first-order L[i, x_i]
//   6-step butterfly; lane 0 adds bias, writes sigmoid.
// V byte offsets fit in u32 (320 MB table) -> global_load with SGPR base +
// 32-bit voffset, no 64-bit vector address adds.
__global__ __launch_bounds__(256) void ffm_kernel(
    const int*   __restrict__ x,     // (BATCH, NFIELDS)
    const float* __restrict__ bias,  // scalar
    const float* __restrict__ L,     // (NFIELDS, VOCAB)
    const float* __restrict__ V,     // (NFIELDS, NFIELDS, VOCAB, EDIM)
    float*       __restrict__ out)   // (BATCH, 1)
{
    const int lane = threadIdx.x & 63;
    const int wave = threadIdx.x >> 6;
    const int b    = blockIdx.x * 4 + wave;   // grid = BATCH/4 blocks exactly

    float acc = 0.0f;

    if (lane < NPAIR) {
        // linear pair index -> (i,j), i<j (F=10)
        int p = lane;
        int i = 0;
        int cnt = NFIELDS - 1;
        while (p >= cnt) { p -= cnt; ++i; --cnt; }
        const int j = i + 1 + p;

        const int xi = x[b * NFIELDS + i];
        const int xj = x[b * NFIELDS + j];

        // u32 byte offsets (max ~320e6 < 2^32)
        const unsigned oa = ((unsigned)(i * NFIELDS + j) * (unsigned)VOCAB
                             + (unsigned)xi) * (unsigned)(EDIM * 4);
        const unsigned ob = ((unsigned)(j * NFIELDS + i) * (unsigned)VOCAB
                             + (unsigned)xj) * (unsigned)(EDIM * 4);
        const float4* va = (const float4*)((const char*)V + oa);
        const float4* vb = (const float4*)((const char*)V + ob);

        // rows are 32B-aligned; 4 independent 16B loads in flight per lane
        const float4 a0 = va[0];
        const float4 a1 = va[1];
        const float4 b0 = vb[0];
        const float4 b1 = vb[1];

        acc = a0.x * b0.x + a0.y * b0.y + a0.z * b0.z + a0.w * b0.w
            + a1.x * b1.x + a1.y * b1.y + a1.z * b1.z + a1.w * b1.w;
    } else if (lane < NPAIR + NFIELDS) {
        const int i  = lane - NPAIR;
        const int xi = x[b * NFIELDS + i];
        acc = L[(unsigned)i * (unsigned)VOCAB + (unsigned)xi];
    }

    // 64-lane butterfly sum (idle lanes carry 0.0f)
    #pragma unroll
    for (int off = 32; off > 0; off >>= 1)
        acc += __shfl_down(acc, off, 64);

    if (lane == 0) {
        const float logit = acc + bias[0];
        out[b] = 1.0f / (1.0f + expf(-logit));
    }
}

extern "C" void kernel_launch(void* const* d_in, const int* in_sizes, int n_in,
                              void* d_out, int out_size, void* d_ws, size_t ws_size,
                              hipStream_t stream) {
    const int*   x    = (const int*)  d_in[0];
    const float* bias = (const float*)d_in[1];
    const float* L    = (const float*)d_in[2];
    const float* V    = (const float*)d_in[3];
    float*       out  = (float*)d_out;

    const int blocks = BATCH / 4;   // 4 waves (items) per 256-thread block
    ffm_kernel<<<blocks, 256, 0, stream>>>(x, bias, L, V, out);
}